// Round 1
// baseline (61442.816 us; speedup 1.0000x reference)
//
#include <hip/hip_runtime.h>

#define L 64
#define TLEN 200000
#define CH 528                        // divisible by 8 (replay unroll); 528 % 8 == 0
#define NCH 379                       // ceil(200000/528); 378*528 = 199584
#define LASTLEN (TLEN - (NCH - 1) * CH)   // 416 (divisible by 8)
#define NEGV -10000.0f
#define STARTT 62
#define STOPT 63

// workspace layout (bytes) — total 123052 < 126940 proven available
#define CKPT_OFF 0                          // float[(NCH+1)*L]  = 97280 B
#define M_OFF ((NCH + 1) * L * 4)           // uchar[NCH*L]      = 24256 B
#define ETAG_OFF (M_OFF + NCH * L)          // int[NCH]          = 1516 B

typedef float f32x4 __attribute__((ext_vector_type(4)));

// Compiler-only fence: orders the vsh ds_write before the next step's ds_reads
// in program order. Hardware ordering is the in-order per-wave DS pipe (same
// guarantee replay_chunk has relied on across all passing runs).
#define STEP_BARRIER() __asm__ volatile("" ::: "memory")

// force v_max3_f32 (3-input max, 1 instruction) — reduce 64->1 in ~34 instrs
__device__ __forceinline__ float max3f(float a, float b, float c) {
    float r;
    __asm__("v_max3_f32 %0, %1, %2, %3" : "=v"(r) : "v"(a), "v"(b), "v"(c));
    return r;
}
__device__ __forceinline__ f32x4 vmax3q(f32x4 a, f32x4 b, f32x4 c) {
    f32x4 r;
    r.x = max3f(a.x, b.x, c.x);
    r.y = max3f(a.y, b.y, c.y);
    r.z = max3f(a.z, b.z, c.z);
    r.w = max3f(a.w, b.w, c.w);
    return r;
}

// constant-index component extract (folds after full unroll; no scratch)
#define QC(q, k) ((k) == 0 ? (q).x : ((k) == 1 ? (q).y : ((k) == 2 ? (q).z : (q).w)))

// ---------------------------------------------------------------------------
// Pass 1: exact sequential forward recurrence — SINGLE WAVE, no barriers, no
// atomics. Lane n owns next-tag n and holds T[n][0..63] in registers; it
// computes the full max over all 64 prev-tags itself:
//   - v[0..15]  arrive via v_readlane SGPR broadcast of vreg (pure VALU path
//     that starts immediately after vreg is produced — hides LDS latency)
//   - v[16..63] arrive via 12 uniform-address ds_read_b128 broadcasts of vsh,
//     ordered after the previous step's single ds_write_b32 by the in-order
//     per-wave DS pipe (no s_barrier, no lgkmcnt drain of a foreign wave).
// Bit-exactness: each score is one RN(v[p]+T[n][p]) exactly as the reference;
// max (incl. v_max3) is order-invariant over finite floats; +feat is rounded
// once at the end: RN(max + f). Checkpoints therefore match the reference
// recurrence bit-for-bit, so the replay kernels are unchanged.
// ---------------------------------------------------------------------------
__global__ __launch_bounds__(64, 1) void k_forward(const float* __restrict__ feats,
                                                   const float* __restrict__ trans,
                                                   float* __restrict__ ckpt) {
    const int n = threadIdx.x;  // 0..63, next-tag owned by this lane

    // T[n][0..63] as 16 quads, fully register-resident
    f32x4 tq[16];
#pragma unroll
    for (int i = 0; i < 16; ++i) tq[i] = reinterpret_cast<const f32x4*>(trans)[n * 16 + i];

    __shared__ __align__(16) float vsh[L];
    const f32x4* vs4 = reinterpret_cast<const f32x4*>(vsh);

    float vreg = (n == STARTT) ? 0.0f : NEGV;  // v_{-1}
    vsh[n] = vreg;
    STEP_BARRIER();

    float fc[8];
#pragma unroll
    for (int j = 0; j < 8; ++j) fc[j] = feats[j * L + n];

#define FWD_STEP(FEAT)                                                         \
    do {                                                                       \
        /* head: p = 0..15 via readlane broadcast (no LDS dependency) */       \
        float h[16];                                                           \
        _Pragma("unroll") for (int p = 0; p < 16; ++p) {                       \
            const float vp = __int_as_float(                                   \
                __builtin_amdgcn_readlane(__float_as_int(vreg), p));           \
            h[p] = vp + QC(tq[p >> 2], p & 3);                                 \
        }                                                                      \
        const float a0 = max3f(h[0], h[1], h[2]);                              \
        const float a1 = max3f(h[3], h[4], h[5]);                              \
        const float a2 = max3f(h[6], h[7], h[8]);                              \
        const float a3 = max3f(h[9], h[10], h[11]);                            \
        const float a4 = max3f(h[12], h[13], h[14]);                           \
        const float mh = fmaxf(max3f(a0, a1, a2), max3f(a3, a4, h[15]));       \
        /* tail: p = 16..63 via broadcast ds_read_b128 (conflict-free) */      \
        const f32x4 s4 = vs4[4] + tq[4];                                       \
        const f32x4 s5 = vs4[5] + tq[5];                                       \
        const f32x4 s6 = vs4[6] + tq[6];                                       \
        const f32x4 s7 = vs4[7] + tq[7];                                       \
        const f32x4 s8 = vs4[8] + tq[8];                                       \
        const f32x4 s9 = vs4[9] + tq[9];                                       \
        const f32x4 s10 = vs4[10] + tq[10];                                    \
        const f32x4 s11 = vs4[11] + tq[11];                                    \
        const f32x4 s12 = vs4[12] + tq[12];                                    \
        const f32x4 s13 = vs4[13] + tq[13];                                    \
        const f32x4 s14 = vs4[14] + tq[14];                                    \
        const f32x4 s15 = vs4[15] + tq[15];                                    \
        const f32x4 c0 = vmax3q(s4, s5, s6);                                   \
        const f32x4 c1 = vmax3q(s7, s8, s9);                                   \
        const f32x4 c2 = vmax3q(s10, s11, s12);                                \
        const f32x4 c3 = vmax3q(s13, s14, s15);                                \
        const f32x4 d0 = vmax3q(c0, c1, c2);                                   \
        f32x4 e;                                                               \
        e.x = fmaxf(d0.x, c3.x);                                               \
        e.y = fmaxf(d0.y, c3.y);                                               \
        e.z = fmaxf(d0.z, c3.z);                                               \
        e.w = fmaxf(d0.w, c3.w);                                               \
        const float m = max3f(max3f(e.x, e.y, e.z), e.w, mh);                  \
        vreg = m + (FEAT);                                                     \
        vsh[n] = vreg;                                                         \
        STEP_BARRIER();                                                        \
    } while (0)

    int nextck = 0, cidx = 0;

    for (int tb = 0; tb < TLEN; tb += 8) {
        if (tb == nextck) {
            // vreg holds v_{tb-1}; CH % 8 == 0 keeps checkpoint hits at block start
            ckpt[cidx * L + n] = vreg;
            nextck += CH;
            ++cidx;
        }
        float fn_[8];
        const bool more = (tb + 8) < TLEN;
        if (more) {
#pragma unroll
            for (int j = 0; j < 8; ++j) fn_[j] = feats[(tb + 8 + j) * L + n];
        }
        FWD_STEP(fc[0]);
        FWD_STEP(fc[1]);
        FWD_STEP(fc[2]);
        FWD_STEP(fc[3]);
        FWD_STEP(fc[4]);
        FWD_STEP(fc[5]);
        FWD_STEP(fc[6]);
        FWD_STEP(fc[7]);
        if (more) {
#pragma unroll
            for (int j = 0; j < 8; ++j) fc[j] = fn_[j];
        }
    }
    // vreg = v_{199999}
    ckpt[NCH * L + n] = vreg;
#undef FWD_STEP
}

// ---------------------------------------------------------------------------
// helpers for the replay kernels (off the critical path, ~0.8 ms total)
// ---------------------------------------------------------------------------
__device__ __forceinline__ void load_trow(const float* __restrict__ trans, int n, float* trow) {
#pragma unroll
    for (int i = 0; i < 16; ++i) {
        const f32x4 q = reinterpret_cast<const f32x4*>(trans)[n * 16 + i];
        trow[4 * i + 0] = q.x;
        trow[4 * i + 1] = q.y;
        trow[4 * i + 2] = q.z;
        trow[4 * i + 3] = q.w;
    }
}

// Bit-exact chunk replay from checkpoint; records backpointers into LDS.
// Single wave per block; in-order DS pipe makes ds_write->ds_read safe with
// only a compiler barrier. Argmax is an in-order strictly-greater scan =>
// first-max, matching jnp.argmax; v matches k_forward bit-for-bit (max is
// order-invariant, +feat monotone-exact).
__device__ __forceinline__ void replay_chunk(const float* __restrict__ feats,
                                             const float* __restrict__ ckpt,
                                             const float* trow, float* vsh,
                                             unsigned char* bpl, int c, int len, int n) {
    float vreg = ckpt[c * L + n];
    vsh[n] = vreg;
    STEP_BARRIER();
    const int base = c * CH;

    float fc[8];
#pragma unroll
    for (int j = 0; j < 8; ++j) fc[j] = feats[(base + j) * L + n];

    for (int sb = 0; sb < len; sb += 8) {
        float fn_[8];
        const bool more = (sb + 8) < len;
        if (more) {
#pragma unroll
            for (int j = 0; j < 8; ++j) fn_[j] = feats[(base + sb + 8 + j) * L + n];
        }
#pragma unroll
        for (int j = 0; j < 8; ++j) {
            float mc[4];
            int ic[4];
#pragma unroll
            for (int g = 0; g < 4; ++g) {
                float m = -INFINITY;
                int idx = g * 16;
#pragma unroll
                for (int r = 0; r < 4; ++r) {
                    const int pb = g * 16 + r * 4;
                    const f32x4 vv = *reinterpret_cast<const f32x4*>(vsh + pb);
                    const float a = vv.x + trow[pb + 0];
                    const float b = vv.y + trow[pb + 1];
                    const float cc = vv.z + trow[pb + 2];
                    const float d = vv.w + trow[pb + 3];
                    if (a > m)  { m = a;  idx = pb + 0; }
                    if (b > m)  { m = b;  idx = pb + 1; }
                    if (cc > m) { m = cc; idx = pb + 2; }
                    if (d > m)  { m = d;  idx = pb + 3; }
                }
                mc[g] = m;
                ic[g] = idx;
            }
            float m = mc[0];
            int idx = ic[0];
            if (mc[1] > m) { m = mc[1]; idx = ic[1]; }
            if (mc[2] > m) { m = mc[2]; idx = ic[2]; }
            if (mc[3] > m) { m = mc[3]; idx = ic[3]; }

            vreg = m + fc[j];
            bpl[(sb + j) * L + n] = (unsigned char)idx;
            vsh[n] = vreg;
            STEP_BARRIER();
        }
        if (more) {
#pragma unroll
            for (int j = 0; j < 8; ++j) fc[j] = fn_[j];
        }
    }
}

// ---------------------------------------------------------------------------
// Pass 2: per-chunk bit-exact replay -> backpointers -> 64-entry chunk map.
// M[c*64+e] = tag at (c*CH - 1) given tag e at the last step of chunk c.
// ---------------------------------------------------------------------------
__global__ __launch_bounds__(64, 1) void k_maps(const float* __restrict__ feats,
                                                const float* __restrict__ trans,
                                                const float* __restrict__ ckpt,
                                                unsigned char* __restrict__ M) {
    const int c = blockIdx.x;
    const int n = threadIdx.x;
    const int len = (c == NCH - 1) ? LASTLEN : CH;

    __shared__ __align__(16) float vsh[L];
    __shared__ unsigned char bpl[CH * L];

    float trow[L];
    load_trow(trans, n, trow);
    replay_chunk(feats, ckpt, trow, vsh, bpl, c, len, n);
    __syncthreads();

    int tag = n;
    for (int s = len - 1; s >= 0; --s) tag = bpl[s * L + tag];
    M[c * L + n] = (unsigned char)tag;
}

// ---------------------------------------------------------------------------
// Pass 3: terminal argmax (bit-exact score) + back-to-front map composition.
// ---------------------------------------------------------------------------
__global__ __launch_bounds__(64, 1) void k_stitch(const float* __restrict__ trans,
                                                  const float* __restrict__ ckpt,
                                                  const unsigned char* __restrict__ M,
                                                  int* __restrict__ etag,
                                                  float* __restrict__ out) {
    const int n = threadIdx.x;
    __shared__ float tsh[L];
    __shared__ int bsh;
    __shared__ __align__(16) unsigned char msh[NCH * L];

    tsh[n] = ckpt[NCH * L + n] + trans[STOPT * L + n];  // terminal[n]
    __syncthreads();
    if (n == 0) {
        float m = tsh[0];
        int b = 0;
        for (int p = 1; p < L; ++p)
            if (tsh[p] > m) { m = tsh[p]; b = p; }  // first-max, like jnp.argmax
        out[0] = m;   // path_score, bit-exact
        bsh = b;
    }
    __syncthreads();

    for (int i = n; i < (NCH * L) / 4; i += L)
        reinterpret_cast<int*>(msh)[i] = reinterpret_cast<const int*>(M)[i];
    __syncthreads();

    if (n == 0) {
        int carry = bsh;  // tag at t = T-1 = end of chunk NCH-1
        for (int c = NCH - 1; c >= 1; --c) {
            etag[c] = carry;
            carry = msh[c * L + carry];
        }
        etag[0] = carry;
    }
}

// ---------------------------------------------------------------------------
// Pass 4: per-chunk replay again, walk backwards from etag[c], emit path.
// Path written as float32 (harness reads the concatenated output as float).
// ---------------------------------------------------------------------------
__global__ __launch_bounds__(64, 1) void k_emit(const float* __restrict__ feats,
                                                const float* __restrict__ trans,
                                                const float* __restrict__ ckpt,
                                                const int* __restrict__ etag,
                                                float* __restrict__ out) {
    const int c = blockIdx.x;
    const int n = threadIdx.x;
    const int len = (c == NCH - 1) ? LASTLEN : CH;

    __shared__ __align__(16) float vsh[L];
    __shared__ unsigned char bpl[CH * L];
    __shared__ unsigned char plc[CH];

    float trow[L];
    load_trow(trans, n, trow);
    replay_chunk(feats, ckpt, trow, vsh, bpl, c, len, n);
    __syncthreads();

    int tag = etag[c];  // uniform; bpl reads below broadcast (same address)
    for (int s = len - 1; s >= 0; --s) {
        if (n == 0) plc[s] = (unsigned char)tag;
        tag = bpl[s * L + tag];
    }
    __syncthreads();

    for (int i = n; i < len; i += L)
        out[1 + c * CH + i] = (float)plc[i];
}

// ---------------------------------------------------------------------------
extern "C" void kernel_launch(void* const* d_in, const int* in_sizes, int n_in,
                              void* d_out, int out_size, void* d_ws, size_t ws_size,
                              hipStream_t stream) {
    const float* feats = (const float*)d_in[0];   // (1, T, L) fp32
    const float* trans = (const float*)d_in[1];   // (L, L) fp32
    float* out = (float*)d_out;                   // [score, path(T) as float]
    char* ws = (char*)d_ws;
    float* ckpt = (float*)(ws + CKPT_OFF);
    unsigned char* M = (unsigned char*)(ws + M_OFF);
    int* etag = (int*)(ws + ETAG_OFF);

    hipLaunchKernelGGL(k_forward, dim3(1), dim3(64), 0, stream, feats, trans, ckpt);
    hipLaunchKernelGGL(k_maps, dim3(NCH), dim3(64), 0, stream, feats, trans, ckpt, M);
    hipLaunchKernelGGL(k_stitch, dim3(1), dim3(64), 0, stream, trans, ckpt, M, etag, out);
    hipLaunchKernelGGL(k_emit, dim3(NCH), dim3(64), 0, stream, feats, trans, ckpt, etag, out);
}